// Round 20
// baseline (128.759 us; speedup 1.0000x reference)
//
#include <hip/hip_runtime.h>
#include <hip/hip_bf16.h>

#define S_LEN 4096
#define DM    768
#define NH    12
#define DKH   64

#define AS1 __attribute__((address_space(1)))
#define AS3 __attribute__((address_space(3)))

typedef __attribute__((ext_vector_type(8))) short short8;
typedef __attribute__((ext_vector_type(4))) float f32x4;

__device__ __forceinline__ short f2bf(float f) {
    union { float f; unsigned u; } v; v.f = f;
    unsigned r = (v.u + 0x7FFFu + ((v.u >> 16) & 1u)) >> 16;
    return (short)r;
}

__device__ __forceinline__ float bf2f(short s) {
    union { unsigned u; float f; } v;
    v.u = ((unsigned)(unsigned short)s) << 16;
    return v.f;
}

#define MFMA16(a, b, c) __builtin_amdgcn_mfma_f32_16x16x32_bf16((a), (b), (c), 0, 0, 0)

// ------------------------------------------------- fused prep (1 dispatch)
__device__ __forceinline__ void cvt4(const float* __restrict__ s,
                                     short* __restrict__ d, int i) {
    float4 v = *reinterpret_cast<const float4*>(s + i);
    short4 o;
    o.x = f2bf(v.x); o.y = f2bf(v.y); o.z = f2bf(v.z); o.w = f2bf(v.w);
    *reinterpret_cast<short4*>(d + i) = o;
}

__global__ __launch_bounds__(256) void prep_k(
    const float* __restrict__ X, const float* __restrict__ Wq,
    const float* __restrict__ Wk, const float* __restrict__ Wv,
    const float* __restrict__ Wo, const int* __restrict__ pos,
    short* __restrict__ Xbf, short* __restrict__ Wqb, short* __restrict__ Wkb,
    short* __restrict__ Wvb, short* __restrict__ Wob, float2* __restrict__ rt) {
    const int bx = blockIdx.x, tid = threadIdx.x;
    if (bx < 3072)      cvt4(X,  Xbf, bx * 1024 + tid * 4);
    else if (bx < 3648) cvt4(Wq, Wqb, (bx - 3072) * 1024 + tid * 4);
    else if (bx < 4224) cvt4(Wk, Wkb, (bx - 3648) * 1024 + tid * 4);
    else if (bx < 4800) cvt4(Wv, Wvb, (bx - 4224) * 1024 + tid * 4);
    else if (bx < 5376) cvt4(Wo, Wob, (bx - 4800) * 1024 + tid * 4);
    else {
        int idx = (bx - 5376) * 256 + tid;
        int s = idx >> 5, i = idx & 31;
        int p = pos[s]; p = p < 0 ? 0 : (p > 4095 ? 4095 : p);
        double inv = pow(10000.0, -(double)i / 32.0);
        float ang = (float)((double)p * inv);
        rt[idx] = make_float2(cosf(ang), sinf(ang));
    }
}

// ---------------------------------------------------------------- GEMM core
// 128x128 tile, BK=64, double-buffered LDS, counted-covered pipeline.
__device__ __forceinline__ void gemm_mainloop(const short* __restrict__ A,
                                              const short* __restrict__ B,
                                              short* Al, short* Bl,
                                              int m0, int n0, int t,
                                              f32x4 acc[4][4]) {
    const int wave = t >> 6, lane = t & 63;
    const int wm = (wave >> 1) * 64, wn = (wave & 1) * 64;
    const int l15 = lane & 15, lg = lane >> 4;
    const int grow = lane >> 3;
    const int gch = (lane & 7) ^ grow;
    const int dsto = wave * 512 + lane * 8;

#define GEMM_STAGE(k0, buf)                                                          \
    {                                                                                \
        _Pragma("unroll")                                                            \
        for (int i = 0; i < 4; ++i) {                                                \
            int row = i * 32 + wave * 8 + grow;                                      \
            __builtin_amdgcn_global_load_lds(                                        \
                (const AS1 void*)&A[(m0 + row) * DM + (k0) + gch * 8],               \
                (AS3 void*)(Al + (buf) * 8192 + i * 2048 + dsto), 16, 0, 0);         \
            __builtin_amdgcn_global_load_lds(                                        \
                (const AS1 void*)&B[(n0 + row) * DM + (k0) + gch * 8],               \
                (AS3 void*)(Bl + (buf) * 8192 + i * 2048 + dsto), 16, 0, 0);         \
        }                                                                            \
    }

    GEMM_STAGE(0, 0);
    asm volatile("s_waitcnt vmcnt(0)" ::: "memory");
    __builtin_amdgcn_s_barrier();

    const int NSTEP = DM / 64;   // 12
    for (int step = 0; step < NSTEP; ++step) {
        const int cur = step & 1;
        if (step + 1 < NSTEP) GEMM_STAGE((step + 1) * 64, cur ^ 1);
        __builtin_amdgcn_sched_barrier(0);
        const short* Ab_ = Al + cur * 8192;
        const short* Bb_ = Bl + cur * 8192;
#pragma unroll
        for (int kh = 0; kh < 2; ++kh) {
            const int c8 = (kh * 4 + lg) ^ (l15 & 7);
            short8 af[4], bf[4];
#pragma unroll
            for (int m = 0; m < 4; ++m)
                af[m] = *reinterpret_cast<const short8*>(Ab_ + (wm + m * 16 + l15) * 64 + c8 * 8);
#pragma unroll
            for (int n = 0; n < 4; ++n)
                bf[n] = *reinterpret_cast<const short8*>(Bb_ + (wn + n * 16 + l15) * 64 + c8 * 8);
#pragma unroll
            for (int m = 0; m < 4; ++m)
#pragma unroll
                for (int n = 0; n < 4; ++n)
                    acc[m][n] = MFMA16(af[m], bf[n], acc[m][n]);
        }
        asm volatile("s_waitcnt vmcnt(0)" ::: "memory");
        __builtin_amdgcn_sched_barrier(0);
        __builtin_amdgcn_s_barrier();
    }
#undef GEMM_STAGE
}

// QKV projection + fused RoPE (+ 1/8*log2e on Q) + fused V-transpose with
// LDS re-transpose epilogue (coalesced Vt stores). grid = (6, 32, 3)
__global__ __launch_bounds__(256) void gemm_qkv_k(
    const short* __restrict__ Xbf, const short* __restrict__ Wq,
    const short* __restrict__ Wk, const short* __restrict__ Wv,
    const float2* __restrict__ rt,
    short* __restrict__ Q, short* __restrict__ K, short* __restrict__ Vt) {
    __shared__ __align__(16) short SM[2 * 128 * 64 * 2];   // 64 KB
    short* Al = SM;
    short* Bl = SM + 2 * 128 * 64;
    const int mat = blockIdx.z;
    const short* B = mat == 0 ? Wq : (mat == 1 ? Wk : Wv);
    const int m0 = blockIdx.y * 128, n0 = blockIdx.x * 128;
    const int t = threadIdx.x;
    f32x4 acc[4][4] = {};
    gemm_mainloop(Xbf, B, Al, Bl, m0, n0, t, acc);
    const int wave = t >> 6, lane = t & 63;
    const int wm = (wave >> 1) * 64, wn = (wave & 1) * 64;
    const int l15 = lane & 15, lg = lane >> 4;
    if (mat < 2) {
        short* Out = mat == 0 ? Q : K;
        const float qs = 0.125f * 1.44269504088896f;
#pragma unroll
        for (int m = 0; m < 4; ++m) {
#pragma unroll
            for (int n = 0; n < 4; ++n) {
                int col = n0 + wn + n * 16 + l15;
                int h = col >> 6, d = col & 63;
#pragma unroll
                for (int j = 0; j < 4; ++j) {
                    int srow = m0 + wm + m * 16 + lg * 4 + j;
                    float v = acc[m][n][j];
                    float other = __shfl_xor(v, 1);
                    float2 cs = rt[srow * 32 + (d >> 1)];
                    v = (d & 1) ? (other * cs.y + v * cs.x)
                                : (v * cs.x - other * cs.y);
                    if (mat == 0) v *= qs;
                    Out[(h * S_LEN + srow) * DKH + d] = f2bf(v);
                }
            }
        }
    } else {
        // V: acc -> LDS transposed tile T[col][row] (pad 136), then
        // coalesced short8 row stores into Vt (contiguous along S).
        short(*T)[136] = (short(*)[136])SM;
#pragma unroll
        for (int m = 0; m < 4; ++m)
#pragma unroll
            for (int n = 0; n < 4; ++n) {
                int cl = wn + n * 16 + l15;
                int rl = wm + m * 16 + lg * 4;
                short4 b;
                b.x = f2bf(acc[m][n][0]); b.y = f2bf(acc[m][n][1]);
                b.z = f2bf(acc[m][n][2]); b.w = f2bf(acc[m][n][3]);
                *reinterpret_cast<short4*>(&T[cl][rl]) = b;
            }
        __syncthreads();
#pragma unroll
        for (int it = 0; it < 8; ++it) {
            int idx = it * 256 + t;
            int dl = idx >> 4;
            int sg = idx & 15;
            short8 v = *reinterpret_cast<const short8*>(&T[dl][sg * 8]);
            int colg = n0 + dl;
            int h = colg >> 6, d = colg & 63;
            *reinterpret_cast<short8*>(
                &Vt[(size_t)(h * DKH + d) * S_LEN + m0 + sg * 8]) = v;
        }
    }
}

// Output projection. grid = (6, 32)
__global__ __launch_bounds__(256) void gemm_out_k(const short* __restrict__ Ab,
                                                  const short* __restrict__ Wo,
                                                  float* __restrict__ out) {
    __shared__ __align__(16) short Al[2 * 128 * 64];
    __shared__ __align__(16) short Bl[2 * 128 * 64];
    const int m0 = blockIdx.y * 128, n0 = blockIdx.x * 128;
    const int t = threadIdx.x;
    f32x4 acc[4][4] = {};
    gemm_mainloop(Ab, Wo, Al, Bl, m0, n0, t, acc);
    const int wave = t >> 6, lane = t & 63;
    const int wm = (wave >> 1) * 64, wn = (wave & 1) * 64;
    const int l15 = lane & 15, lg = lane >> 4;
#pragma unroll
    for (int m = 0; m < 4; ++m)
#pragma unroll
        for (int n = 0; n < 4; ++n)
#pragma unroll
            for (int j = 0; j < 4; ++j) {
                int srow = m0 + wm + m * 16 + lg * 4 + j;
                int col = n0 + wn + n * 16 + l15;
                out[srow * DM + col] = acc[m][n][j];
            }
}

// ---------------------------------------------------------------- attention
__device__ __forceinline__ void stage64(const short* __restrict__ gRow0,
                                        int rowStride, short* lbuf,
                                        int wave, int lane) {
#pragma unroll
    for (int i = 0; i < 2; ++i) {
        int c = wave + i * 4;                     // 1KB chunk 0..7
        int row = c * 8 + (lane >> 3);            // tile row 0..63
        int gch = (lane & 7) ^ (lane >> 3);       // swizzled 16B chunk in row
        const short* src = gRow0 + (long)row * rowStride + gch * 8;
        short* dst = lbuf + c * 512 + lane * 8;   // linear: row*64 + chunk*8
        __builtin_amdgcn_global_load_lds(
            (const AS1 void*)src, (AS3 void*)dst, 16, 0, 0);
    }
}

// Flash-decoding split attention (KVBLK=64, 40KB LDS, bf16 partials).
// Softmax bias folded into MFMA C-init: s = QK^T - mrun directly from the
// matrix pipe (no VALU subs on the common path); mrun starts at 0.
// l-sum on the matrix pipe via ones-fragment.
//  sid <  32 : qb = 63-sid,      seg0 tiles [0,32)   -> partial
//  sid <  64 : qb = 95-sid,      seg1 tiles [32,qb+1) -> partial
//  sid >= 64 : qb = 95-sid (31..0), tiles [0,qb+1)   -> direct write
__global__ __launch_bounds__(256) void attn_k(const short* __restrict__ Q,
                                              const short* __restrict__ K,
                                              const short* __restrict__ Vt,
                                              short* __restrict__ Aout,
                                              short* __restrict__ Op,
                                              float2* __restrict__ Mp) {
    const int bx = blockIdx.x;
    const int h = bx % NH;
    const int sid = bx / NH;
    const int qb = (sid < 32) ? (63 - sid) : (95 - sid);
    const bool partial = (sid < 64);
    const int seg = (sid >= 32 && sid < 64) ? 1 : 0;
    const int t0 = seg ? 32 : 0;
    const int t1 = (sid < 32) ? 32 : (qb + 1);

    const int t = threadIdx.x;
    const int wave = t >> 6, lane = t & 63;
    const int l15 = lane & 15, lg = lane >> 4;
    const int q0w = qb * 64 + wave * 16;

    __shared__ __align__(16) short KVl[2][2][64 * 64];  // 32 KB [buf][K|V]
    __shared__ __align__(16) short Pl[4][16][64];       // 8 KB, chunk-XOR swz

    const short* Kh = K + (size_t)h * S_LEN * DKH;
    const short* Vh = Vt + (size_t)h * DKH * S_LEN;

    short8 qf[2];
#pragma unroll
    for (int ks = 0; ks < 2; ++ks)
        qf[ks] = *reinterpret_cast<const short8*>(
            &Q[(h * S_LEN + q0w + l15) * DKH + ks * 32 + lg * 8]);

    short8 onesv;
#pragma unroll
    for (int e = 0; e < 8; ++e) onesv[e] = (short)0x3F80;   // bf16 1.0

    f32x4 o[4] = {};
    f32x4 lacc = {};                       // matrix-pipe l-sum accumulator
    float mrun = 0.f;                      // bias; p = exp2(score - mrun)

    stage64(Kh + (size_t)t0 * 64 * DKH, DKH, KVl[0][0], wave, lane);
    stage64(Vh + t0 * 64, S_LEN, KVl[0][1], wave, lane);
    __syncthreads();

    for (int tile = t0; tile < t1; ++tile) {
        const int cur = (tile - t0) & 1;
        if (tile + 1 < t1) {
            stage64(Kh + (size_t)(tile + 1) * 64 * DKH, DKH, KVl[cur ^ 1][0], wave, lane);
            stage64(Vh + (tile + 1) * 64, S_LEN, KVl[cur ^ 1][1], wave, lane);
        }
        __builtin_amdgcn_sched_barrier(0);   // pin issue point
        const char* Kb = (const char*)KVl[cur][0];
        const char* Vb = (const char*)KVl[cur][1];

        // ---- S^T = K Q^T - mrun (bias via MFMA C-init; Q pre-scaled)
        const float nb = -mrun;
        f32x4 s[4];
#pragma unroll
        for (int n = 0; n < 4; ++n) {
            s[n][0] = nb; s[n][1] = nb; s[n][2] = nb; s[n][3] = nb;
        }
        __builtin_amdgcn_s_setprio(1);
#pragma unroll
        for (int ks = 0; ks < 2; ++ks)
#pragma unroll
            for (int n = 0; n < 4; ++n) {
                int r = n * 16 + l15;
                int c8 = (ks * 4 + lg) ^ (r & 7);
                short8 kf = *reinterpret_cast<const short8*>(Kb + r * 128 + c8 * 16);
                s[n] = MFMA16(kf, qf[ks], s[n]);
            }
        __builtin_amdgcn_s_setprio(0);

        // ---- causal mask (diagonal tile only)
        if (tile == qb) {
            const int q = q0w + l15;
#pragma unroll
            for (int n = 0; n < 4; ++n)
#pragma unroll
                for (int j = 0; j < 4; ++j)
                    if (tile * 64 + n * 16 + lg * 4 + j > q) s[n][j] = -1e30f;
        }

        // ---- per-lane local max of biased scores; defer: no cross-lane ops
        float mt = fmaxf(fmaxf(fmaxf(s[0][0], s[0][1]), fmaxf(s[0][2], s[0][3])),
                         fmaxf(fmaxf(s[1][0], s[1][1]), fmaxf(s[1][2], s[1][3])));
        mt = fmaxf(mt, fmaxf(fmaxf(fmaxf(s[2][0], s[2][1]), fmaxf(s[2][2], s[2][3])),
                             fmaxf(fmaxf(s[3][0], s[3][1]), fmaxf(s[3][2], s[3][3]))));

        if (__all(mt <= 8.f)) {
            // defer: p = exp2(score - mrun) = exp2(s) directly (NO subs)
#pragma unroll
            for (int n = 0; n < 4; ++n)
#pragma unroll
                for (int j = 0; j < 4; ++j)
                    s[n][j] = exp2f(s[n][j]);
        } else {
            float mm = fmaxf(mt, __shfl_xor(mt, 16));
            mm = fmaxf(mm, __shfl_xor(mm, 32));
            float d = fmaxf(mm, 0.f);          // row-uniform shift
            float alpha = exp2f(-d);
#pragma unroll
            for (int n = 0; n < 4; ++n)
#pragma unroll
                for (int j = 0; j < 4; ++j)
                    s[n][j] = exp2f(s[n][j] - d);
#pragma unroll
            for (int n = 0; n < 4; ++n)
#pragma unroll
                for (int j = 0; j < 4; ++j) o[n][j] *= alpha;
            lacc *= alpha;
            mrun += d;
        }

        // ---- P^T -> per-wave LDS, 16B-chunk XOR swizzle (stride 64)
#pragma unroll
        for (int n = 0; n < 4; ++n) {
            unsigned p0, p1;
            asm("v_cvt_pk_bf16_f32 %0, %1, %2" : "=v"(p0) : "v"(s[n][0]), "v"(s[n][1]));
            asm("v_cvt_pk_bf16_f32 %0, %1, %2" : "=v"(p1) : "v"(s[n][2]), "v"(s[n][3]));
            uint2 w; w.x = p0; w.y = p1;
            int cw = (n * 2 + (lg >> 1)) ^ (l15 & 7);
            *reinterpret_cast<uint2*>(&Pl[wave][l15][cw * 8 + (lg & 1) * 4]) = w;
        }

        // ---- O^T += V^T P^T ; l-sum via ones-fragment on matrix pipe
        __builtin_amdgcn_s_setprio(1);
#pragma unroll
        for (int ks = 0; ks < 2; ++ks) {
            int cr = (ks * 4 + lg) ^ (l15 & 7);
            short8 pa = *reinterpret_cast<const short8*>(&Pl[wave][l15][cr * 8]);
            lacc = MFMA16(onesv, pa, lacc);
#pragma unroll
            for (int n = 0; n < 4; ++n) {
                int r = n * 16 + l15;
                int c8 = (ks * 4 + lg) ^ (r & 7);
                short8 vf = *reinterpret_cast<const short8*>(Vb + r * 128 + c8 * 16);
                o[n] = MFMA16(vf, pa, o[n]);
            }
        }
        __builtin_amdgcn_s_setprio(0);

        // ---- covered fence + raw barrier (no early drain)
        asm volatile("s_waitcnt vmcnt(0)" ::: "memory");
        __builtin_amdgcn_sched_barrier(0);
        __builtin_amdgcn_s_barrier();
    }

    // ---- l-sum complete per-lane (all rows of lacc identical)
    float lsum = lacc[0];

    __syncthreads();   // safe LDS reuse for epilogue
    float* Ol = (float*)&KVl[0][0][0] + wave * (16 * 68);

    if (partial) {
        // unnormalized O^T -> LDS transpose -> coalesced bf16 partial store
#pragma unroll
        for (int n = 0; n < 4; ++n) {
            float4 w;
            w.x = o[n][0]; w.y = o[n][1]; w.z = o[n][2]; w.w = o[n][3];
            *reinterpret_cast<float4*>(&Ol[l15 * 68 + n * 16 + lg * 4]) = w;
        }
        const size_t rowbase = ((size_t)h * 32 + (qb - 32)) * 64;
        const size_t segR = (size_t)NH * 32 * 64;
        if (lane < 16)
            Mp[seg * segR + rowbase + wave * 16 + l15] = make_float2(mrun, lsum);
#pragma unroll
        for (int kk = 0; kk < 2; ++kk) {
            int r = (lane >> 3) + kk * 8;         // 0..15
            int c0 = (lane & 7) * 8;              // 8-col group
            float4 a = *reinterpret_cast<const float4*>(&Ol[r * 68 + c0]);
            float4 b = *reinterpret_cast<const float4*>(&Ol[r * 68 + c0 + 4]);
            short8 v;
            v[0] = f2bf(a.x); v[1] = f2bf(a.y); v[2] = f2bf(a.z); v[3] = f2bf(a.w);
            v[4] = f2bf(b.x); v[5] = f2bf(b.y); v[6] = f2bf(b.z); v[7] = f2bf(b.w);
            *reinterpret_cast<short8*>(
                &Op[(seg * segR + rowbase + wave * 16 + r) * 64 + c0]) = v;
        }
    } else {
        float inv = 1.f / lsum;
#pragma unroll
        for (int n = 0; n < 4; ++n) {
            float4 w;
            w.x = o[n][0] * inv; w.y = o[n][1] * inv;
            w.z = o[n][2] * inv; w.w = o[n][3] * inv;
            *reinterpret_cast<float4*>(&Ol[l15 * 68 + n * 16 + lg * 4]) = w;
        }
#pragma unroll
        for (int kk = 0; kk < 4; ++kk) {
            int r = lane >> 2, c0 = (lane & 3) * 4 + kk * 16;
            float4 v = *reinterpret_cast<const float4*>(&Ol[r * 68 + c0]);
            short4 b;
            b.x = f2bf(v.x); b.y = f2bf(v.y); b.z = f2bf(v.z); b.w = f2bf(v.w);
            *reinterpret_cast<short4*>(
                &Aout[(size_t)(q0w + r) * DM + h * DKH + c0]) = b;
        }
    }
}

// Merge the 2 kv-segments for qb >= 32 (bf16 partials). grid = 12*32 x 256.
__global__ __launch_bounds__(256) void combine_k(const short* __restrict__ Op,
                                                 const float2* __restrict__ Mp,
                                                 short* __restrict__ Aout) {
    const int h = blockIdx.x / 32, qbr = blockIdx.x % 32;
    const int t = threadIdx.x;
    const int row = t >> 2, c0 = (t & 3) * 16;
    const size_t rowbase = ((size_t)h * 32 + qbr) * 64 + row;
    const size_t segR = (size_t)NH * 32 * 64;
    float2 ml0 = Mp[rowbase], ml1 = Mp[segR + rowbase];
    float m = fmaxf(ml0.x, ml1.x);
    float s0 = exp2f(ml0.x - m), s1 = exp2f(ml1.x - m);
    float inv = 1.f / (s0 * ml0.y + s1 * ml1.y);
    const short* O0 = Op + rowbase * 64;
    const short* O1 = Op + (segR + rowbase) * 64;
    const int q = (32 + qbr) * 64 + row;
#pragma unroll
    for (int i = 0; i < 2; ++i) {
        int d = c0 + i * 8;
        short8 a = *reinterpret_cast<const short8*>(O0 + d);
        short8 b = *reinterpret_cast<const short8*>(O1 + d);
        short8 r;
#pragma unroll
        for (int e = 0; e < 8; ++e)
            r[e] = f2bf((bf2f(a[e]) * s0 + bf2f(b[e]) * s1) * inv);
        *reinterpret_cast<short8*>(&Aout[(size_t)q * DM + h * DKH + d]) = r;
    }
}

// ---------------------------------------------------------------- launcher
extern "C" void kernel_launch(void* const* d_in, const int* in_sizes, int n_in,
                              void* d_out, int out_size, void* d_ws, size_t ws_size,
                              hipStream_t stream) {
    const float* X  = (const float*)d_in[0];
    const int*   pos = (const int*)d_in[1];
    const float* Wq = (const float*)d_in[2];
    const float* Wk = (const float*)d_in[3];
    const float* Wv = (const float*)d_in[4];
    const float* Wo = (const float*)d_in[5];
    float* out = (float*)d_out;

    char* ws = (char*)d_ws;
    short* Xbf = (short*)ws;  ws += (size_t)S_LEN * DM * 2;
    short* Wqb = (short*)ws;  ws += (size_t)DM * DM * 2;
    short* Wkb = (short*)ws;  ws += (size_t)DM * DM * 2;
    short* Wvb = (short*)ws;  ws += (size_t)DM * DM * 2;
    short* Wob = (short*)ws;  ws += (size_t)DM * DM * 2;
    float2* rt = (float2*)ws; ws += (size_t)S_LEN * 32 * 8;
    short* Qb  = (short*)ws;  ws += (size_t)NH * S_LEN * DKH * 2;
    short* Kb  = (short*)ws;  ws += (size_t)NH * S_LEN * DKH * 2;
    short* Vtb = (short*)ws;  ws += (size_t)NH * S_LEN * DKH * 2;
    short* Ab  = (short*)ws;  ws += (size_t)S_LEN * DM * 2;
    short* Op  = (short*)ws;  ws += (size_t)2 * NH * 32 * 64 * 64 * 2;  // 6.3 MB
    float2* Mp = (float2*)ws; ws += (size_t)2 * NH * 32 * 64 * 8;       // 0.4 MB

    prep_k<<<5888, 256, 0, stream>>>(X, Wq, Wk, Wv, Wo, pos,
                                     Xbf, Wqb, Wkb, Wvb, Wob, rt);
    gemm_qkv_k<<<dim3(6, 32, 3), 256, 0, stream>>>(Xbf, Wqb, Wkb, Wvb, rt, Qb, Kb, Vtb);
    attn_k<<<dim3(96 * NH), 256, 0, stream>>>(Qb, Kb, Vtb, Ab, Op, Mp);
    combine_k<<<dim3(NH * 32), 256, 0, stream>>>(Op, Mp, Ab);
    gemm_out_k<<<dim3(6, 32), 256, 0, stream>>>(Ab, Wob, out);
}

// Round 21
// 123.967 us; speedup vs baseline: 1.0387x; 1.0387x over previous
//
#include <hip/hip_runtime.h>
#include <hip/hip_bf16.h>

#define S_LEN 4096
#define DM    768
#define NH    12
#define DKH   64

#define AS1 __attribute__((address_space(1)))
#define AS3 __attribute__((address_space(3)))

typedef __attribute__((ext_vector_type(8))) short short8;
typedef __attribute__((ext_vector_type(4))) float f32x4;

__device__ __forceinline__ short f2bf(float f) {
    union { float f; unsigned u; } v; v.f = f;
    unsigned r = (v.u + 0x7FFFu + ((v.u >> 16) & 1u)) >> 16;
    return (short)r;
}

__device__ __forceinline__ float bf2f(short s) {
    union { unsigned u; float f; } v;
    v.u = ((unsigned)(unsigned short)s) << 16;
    return v.f;
}

#define MFMA16(a, b, c) __builtin_amdgcn_mfma_f32_16x16x32_bf16((a), (b), (c), 0, 0, 0)

// ------------------------------------------------- fused prep (1 dispatch)
__device__ __forceinline__ void cvt4(const float* __restrict__ s,
                                     short* __restrict__ d, int i) {
    float4 v = *reinterpret_cast<const float4*>(s + i);
    short4 o;
    o.x = f2bf(v.x); o.y = f2bf(v.y); o.z = f2bf(v.z); o.w = f2bf(v.w);
    *reinterpret_cast<short4*>(d + i) = o;
}

__global__ __launch_bounds__(256) void prep_k(
    const float* __restrict__ X, const float* __restrict__ Wq,
    const float* __restrict__ Wk, const float* __restrict__ Wv,
    const float* __restrict__ Wo, const int* __restrict__ pos,
    short* __restrict__ Xbf, short* __restrict__ Wqb, short* __restrict__ Wkb,
    short* __restrict__ Wvb, short* __restrict__ Wob, float2* __restrict__ rt) {
    const int bx = blockIdx.x, tid = threadIdx.x;
    if (bx < 3072)      cvt4(X,  Xbf, bx * 1024 + tid * 4);
    else if (bx < 3648) cvt4(Wq, Wqb, (bx - 3072) * 1024 + tid * 4);
    else if (bx < 4224) cvt4(Wk, Wkb, (bx - 3648) * 1024 + tid * 4);
    else if (bx < 4800) cvt4(Wv, Wvb, (bx - 4224) * 1024 + tid * 4);
    else if (bx < 5376) cvt4(Wo, Wob, (bx - 4800) * 1024 + tid * 4);
    else {
        int idx = (bx - 5376) * 256 + tid;
        int s = idx >> 5, i = idx & 31;
        int p = pos[s]; p = p < 0 ? 0 : (p > 4095 ? 4095 : p);
        double inv = pow(10000.0, -(double)i / 32.0);
        float ang = (float)((double)p * inv);
        rt[idx] = make_float2(cosf(ang), sinf(ang));
    }
}

// ---------------------------------------------------------------- GEMM core
// 128x128 tile, BK=64, double-buffered LDS, counted-covered pipeline.
__device__ __forceinline__ void gemm_mainloop(const short* __restrict__ A,
                                              const short* __restrict__ B,
                                              short* Al, short* Bl,
                                              int m0, int n0, int t,
                                              f32x4 acc[4][4]) {
    const int wave = t >> 6, lane = t & 63;
    const int wm = (wave >> 1) * 64, wn = (wave & 1) * 64;
    const int l15 = lane & 15, lg = lane >> 4;
    const int grow = lane >> 3;
    const int gch = (lane & 7) ^ grow;
    const int dsto = wave * 512 + lane * 8;

#define GEMM_STAGE(k0, buf)                                                          \
    {                                                                                \
        _Pragma("unroll")                                                            \
        for (int i = 0; i < 4; ++i) {                                                \
            int row = i * 32 + wave * 8 + grow;                                      \
            __builtin_amdgcn_global_load_lds(                                        \
                (const AS1 void*)&A[(m0 + row) * DM + (k0) + gch * 8],               \
                (AS3 void*)(Al + (buf) * 8192 + i * 2048 + dsto), 16, 0, 0);         \
            __builtin_amdgcn_global_load_lds(                                        \
                (const AS1 void*)&B[(n0 + row) * DM + (k0) + gch * 8],               \
                (AS3 void*)(Bl + (buf) * 8192 + i * 2048 + dsto), 16, 0, 0);         \
        }                                                                            \
    }

    GEMM_STAGE(0, 0);
    asm volatile("s_waitcnt vmcnt(0)" ::: "memory");
    __builtin_amdgcn_s_barrier();

    const int NSTEP = DM / 64;   // 12
    for (int step = 0; step < NSTEP; ++step) {
        const int cur = step & 1;
        if (step + 1 < NSTEP) GEMM_STAGE((step + 1) * 64, cur ^ 1);
        __builtin_amdgcn_sched_barrier(0);
        const short* Ab_ = Al + cur * 8192;
        const short* Bb_ = Bl + cur * 8192;
#pragma unroll
        for (int kh = 0; kh < 2; ++kh) {
            const int c8 = (kh * 4 + lg) ^ (l15 & 7);
            short8 af[4], bf[4];
#pragma unroll
            for (int m = 0; m < 4; ++m)
                af[m] = *reinterpret_cast<const short8*>(Ab_ + (wm + m * 16 + l15) * 64 + c8 * 8);
#pragma unroll
            for (int n = 0; n < 4; ++n)
                bf[n] = *reinterpret_cast<const short8*>(Bb_ + (wn + n * 16 + l15) * 64 + c8 * 8);
#pragma unroll
            for (int m = 0; m < 4; ++m)
#pragma unroll
                for (int n = 0; n < 4; ++n)
                    acc[m][n] = MFMA16(af[m], bf[n], acc[m][n]);
        }
        asm volatile("s_waitcnt vmcnt(0)" ::: "memory");
        __builtin_amdgcn_sched_barrier(0);
        __builtin_amdgcn_s_barrier();
    }
#undef GEMM_STAGE
}

// QKV projection + fused RoPE (+ 1/8*log2e on Q) + fused V-transpose with
// LDS re-transpose epilogue (coalesced Vt stores). grid = (6, 32, 3)
__global__ __launch_bounds__(256) void gemm_qkv_k(
    const short* __restrict__ Xbf, const short* __restrict__ Wq,
    const short* __restrict__ Wk, const short* __restrict__ Wv,
    const float2* __restrict__ rt,
    short* __restrict__ Q, short* __restrict__ K, short* __restrict__ Vt) {
    __shared__ __align__(16) short SM[2 * 128 * 64 * 2];   // 64 KB
    short* Al = SM;
    short* Bl = SM + 2 * 128 * 64;
    const int mat = blockIdx.z;
    const short* B = mat == 0 ? Wq : (mat == 1 ? Wk : Wv);
    const int m0 = blockIdx.y * 128, n0 = blockIdx.x * 128;
    const int t = threadIdx.x;
    f32x4 acc[4][4] = {};
    gemm_mainloop(Xbf, B, Al, Bl, m0, n0, t, acc);
    const int wave = t >> 6, lane = t & 63;
    const int wm = (wave >> 1) * 64, wn = (wave & 1) * 64;
    const int l15 = lane & 15, lg = lane >> 4;
    if (mat < 2) {
        short* Out = mat == 0 ? Q : K;
        const float qs = 0.125f * 1.44269504088896f;
#pragma unroll
        for (int m = 0; m < 4; ++m) {
#pragma unroll
            for (int n = 0; n < 4; ++n) {
                int col = n0 + wn + n * 16 + l15;
                int h = col >> 6, d = col & 63;
#pragma unroll
                for (int j = 0; j < 4; ++j) {
                    int srow = m0 + wm + m * 16 + lg * 4 + j;
                    float v = acc[m][n][j];
                    float other = __shfl_xor(v, 1);
                    float2 cs = rt[srow * 32 + (d >> 1)];
                    v = (d & 1) ? (other * cs.y + v * cs.x)
                                : (v * cs.x - other * cs.y);
                    if (mat == 0) v *= qs;
                    Out[(h * S_LEN + srow) * DKH + d] = f2bf(v);
                }
            }
        }
    } else {
        // V: acc -> LDS transposed tile T[col][row] (pad 136), then
        // coalesced short8 row stores into Vt (contiguous along S).
        short(*T)[136] = (short(*)[136])SM;
#pragma unroll
        for (int m = 0; m < 4; ++m)
#pragma unroll
            for (int n = 0; n < 4; ++n) {
                int cl = wn + n * 16 + l15;
                int rl = wm + m * 16 + lg * 4;
                short4 b;
                b.x = f2bf(acc[m][n][0]); b.y = f2bf(acc[m][n][1]);
                b.z = f2bf(acc[m][n][2]); b.w = f2bf(acc[m][n][3]);
                *reinterpret_cast<short4*>(&T[cl][rl]) = b;
            }
        __syncthreads();
#pragma unroll
        for (int it = 0; it < 8; ++it) {
            int idx = it * 256 + t;
            int dl = idx >> 4;
            int sg = idx & 15;
            short8 v = *reinterpret_cast<const short8*>(&T[dl][sg * 8]);
            int colg = n0 + dl;
            int h = colg >> 6, d = colg & 63;
            *reinterpret_cast<short8*>(
                &Vt[(size_t)(h * DKH + d) * S_LEN + m0 + sg * 8]) = v;
        }
    }
}

// Output projection. grid = (6, 32)
__global__ __launch_bounds__(256) void gemm_out_k(const short* __restrict__ Ab,
                                                  const short* __restrict__ Wo,
                                                  float* __restrict__ out) {
    __shared__ __align__(16) short Al[2 * 128 * 64];
    __shared__ __align__(16) short Bl[2 * 128 * 64];
    const int m0 = blockIdx.y * 128, n0 = blockIdx.x * 128;
    const int t = threadIdx.x;
    f32x4 acc[4][4] = {};
    gemm_mainloop(Ab, Wo, Al, Bl, m0, n0, t, acc);
    const int wave = t >> 6, lane = t & 63;
    const int wm = (wave >> 1) * 64, wn = (wave & 1) * 64;
    const int l15 = lane & 15, lg = lane >> 4;
#pragma unroll
    for (int m = 0; m < 4; ++m)
#pragma unroll
        for (int n = 0; n < 4; ++n)
#pragma unroll
            for (int j = 0; j < 4; ++j) {
                int srow = m0 + wm + m * 16 + lg * 4 + j;
                int col = n0 + wn + n * 16 + l15;
                out[srow * DM + col] = acc[m][n][j];
            }
}

// ---------------------------------------------------------------- attention
__device__ __forceinline__ void stage64(const short* __restrict__ gRow0,
                                        int rowStride, short* lbuf,
                                        int wave, int lane) {
#pragma unroll
    for (int i = 0; i < 2; ++i) {
        int c = wave + i * 4;                     // 1KB chunk 0..7
        int row = c * 8 + (lane >> 3);            // tile row 0..63
        int gch = (lane & 7) ^ (lane >> 3);       // swizzled 16B chunk in row
        const short* src = gRow0 + (long)row * rowStride + gch * 8;
        short* dst = lbuf + c * 512 + lane * 8;   // linear: row*64 + chunk*8
        __builtin_amdgcn_global_load_lds(
            (const AS1 void*)src, (AS3 void*)dst, 16, 0, 0);
    }
}

// Flash-decoding split attention (KVBLK=64, 40KB LDS, bf16 partials).
// l-sum computed on the MATRIX pipe via an all-ones A-fragment
// (lacc = mfma(1, P, lacc)) -> no VALU adds, no end shuffles.
//  sid <  32 : qb = 63-sid,      seg0 tiles [0,32)   -> partial
//  sid <  64 : qb = 95-sid,      seg1 tiles [32,qb+1) -> partial
//  sid >= 64 : qb = 95-sid (31..0), tiles [0,qb+1)   -> direct write
__global__ __launch_bounds__(256) void attn_k(const short* __restrict__ Q,
                                              const short* __restrict__ K,
                                              const short* __restrict__ Vt,
                                              short* __restrict__ Aout,
                                              short* __restrict__ Op,
                                              float2* __restrict__ Mp) {
    const int bx = blockIdx.x;
    const int h = bx % NH;
    const int sid = bx / NH;
    const int qb = (sid < 32) ? (63 - sid) : (95 - sid);
    const bool partial = (sid < 64);
    const int seg = (sid >= 32 && sid < 64) ? 1 : 0;
    const int t0 = seg ? 32 : 0;
    const int t1 = (sid < 32) ? 32 : (qb + 1);

    const int t = threadIdx.x;
    const int wave = t >> 6, lane = t & 63;
    const int l15 = lane & 15, lg = lane >> 4;
    const int q0w = qb * 64 + wave * 16;

    __shared__ __align__(16) short KVl[2][2][64 * 64];  // 32 KB [buf][K|V]
    __shared__ __align__(16) short Pl[4][16][64];       // 8 KB, chunk-XOR swz

    const short* Kh = K + (size_t)h * S_LEN * DKH;
    const short* Vh = Vt + (size_t)h * DKH * S_LEN;

    short8 qf[2];
#pragma unroll
    for (int ks = 0; ks < 2; ++ks)
        qf[ks] = *reinterpret_cast<const short8*>(
            &Q[(h * S_LEN + q0w + l15) * DKH + ks * 32 + lg * 8]);

    short8 onesv;
#pragma unroll
    for (int e = 0; e < 8; ++e) onesv[e] = (short)0x3F80;   // bf16 1.0

    f32x4 o[4] = {};
    f32x4 lacc = {};                       // matrix-pipe l-sum accumulator
    float mrun = -1e30f;

    stage64(Kh + (size_t)t0 * 64 * DKH, DKH, KVl[0][0], wave, lane);
    stage64(Vh + t0 * 64, S_LEN, KVl[0][1], wave, lane);
    __syncthreads();

    for (int tile = t0; tile < t1; ++tile) {
        const int cur = (tile - t0) & 1;
        if (tile + 1 < t1) {
            stage64(Kh + (size_t)(tile + 1) * 64 * DKH, DKH, KVl[cur ^ 1][0], wave, lane);
            stage64(Vh + (tile + 1) * 64, S_LEN, KVl[cur ^ 1][1], wave, lane);
        }
        __builtin_amdgcn_sched_barrier(0);   // pin issue point
        const char* Kb = (const char*)KVl[cur][0];
        const char* Vb = (const char*)KVl[cur][1];

        // ---- S^T = K Q^T (Q pre-scaled by 1/8*log2e)
        f32x4 s[4] = {};
        __builtin_amdgcn_s_setprio(1);
#pragma unroll
        for (int ks = 0; ks < 2; ++ks)
#pragma unroll
            for (int n = 0; n < 4; ++n) {
                int r = n * 16 + l15;
                int c8 = (ks * 4 + lg) ^ (r & 7);
                short8 kf = *reinterpret_cast<const short8*>(Kb + r * 128 + c8 * 16);
                s[n] = MFMA16(kf, qf[ks], s[n]);
            }
        __builtin_amdgcn_s_setprio(0);

        // ---- causal mask (diagonal tile only)
        if (tile == qb) {
            const int q = q0w + l15;
#pragma unroll
            for (int n = 0; n < 4; ++n)
#pragma unroll
                for (int j = 0; j < 4; ++j)
                    if (tile * 64 + n * 16 + lg * 4 + j > q) s[n][j] = -1e30f;
        }

        // ---- per-lane local max; defer path has NO cross-lane ops
        float mt = fmaxf(fmaxf(fmaxf(s[0][0], s[0][1]), fmaxf(s[0][2], s[0][3])),
                         fmaxf(fmaxf(s[1][0], s[1][1]), fmaxf(s[1][2], s[1][3])));
        mt = fmaxf(mt, fmaxf(fmaxf(fmaxf(s[2][0], s[2][1]), fmaxf(s[2][2], s[2][3])),
                             fmaxf(fmaxf(s[3][0], s[3][1]), fmaxf(s[3][2], s[3][3]))));

        if (__all(mt <= mrun + 8.f)) {
#pragma unroll
            for (int n = 0; n < 4; ++n)
#pragma unroll
                for (int j = 0; j < 4; ++j)
                    s[n][j] = exp2f(s[n][j] - mrun);
        } else {
            float mm = fmaxf(mt, __shfl_xor(mt, 16));
            mm = fmaxf(mm, __shfl_xor(mm, 32));
            float mnew = fmaxf(mrun, mm);
            float alpha = exp2f(mrun - mnew);
#pragma unroll
            for (int n = 0; n < 4; ++n)
#pragma unroll
                for (int j = 0; j < 4; ++j)
                    s[n][j] = exp2f(s[n][j] - mnew);
#pragma unroll
            for (int n = 0; n < 4; ++n)
#pragma unroll
                for (int j = 0; j < 4; ++j) o[n][j] *= alpha;
            lacc *= alpha;
            mrun = mnew;
        }

        // ---- P^T -> per-wave LDS, 16B-chunk XOR swizzle (stride 64)
#pragma unroll
        for (int n = 0; n < 4; ++n) {
            unsigned p0, p1;
            asm("v_cvt_pk_bf16_f32 %0, %1, %2" : "=v"(p0) : "v"(s[n][0]), "v"(s[n][1]));
            asm("v_cvt_pk_bf16_f32 %0, %1, %2" : "=v"(p1) : "v"(s[n][2]), "v"(s[n][3]));
            uint2 w; w.x = p0; w.y = p1;
            int cw = (n * 2 + (lg >> 1)) ^ (l15 & 7);
            *reinterpret_cast<uint2*>(&Pl[wave][l15][cw * 8 + (lg & 1) * 4]) = w;
        }

        // ---- O^T += V^T P^T ; l-sum via ones-fragment on matrix pipe
        __builtin_amdgcn_s_setprio(1);
#pragma unroll
        for (int ks = 0; ks < 2; ++ks) {
            int cr = (ks * 4 + lg) ^ (l15 & 7);
            short8 pa = *reinterpret_cast<const short8*>(&Pl[wave][l15][cr * 8]);
            lacc = MFMA16(onesv, pa, lacc);
#pragma unroll
            for (int n = 0; n < 4; ++n) {
                int r = n * 16 + l15;
                int c8 = (ks * 4 + lg) ^ (r & 7);
                short8 vf = *reinterpret_cast<const short8*>(Vb + r * 128 + c8 * 16);
                o[n] = MFMA16(vf, pa, o[n]);
            }
        }
        __builtin_amdgcn_s_setprio(0);

        // ---- covered fence + raw barrier (no early drain)
        asm volatile("s_waitcnt vmcnt(0)" ::: "memory");
        __builtin_amdgcn_sched_barrier(0);
        __builtin_amdgcn_s_barrier();
    }

    // ---- l-sum already complete per-lane (all rows of lacc identical)
    float lsum = lacc[0];

    __syncthreads();   // safe LDS reuse for epilogue
    float* Ol = (float*)&KVl[0][0][0] + wave * (16 * 68);

    if (partial) {
        // unnormalized O^T -> LDS transpose -> coalesced bf16 partial store
#pragma unroll
        for (int n = 0; n < 4; ++n) {
            float4 w;
            w.x = o[n][0]; w.y = o[n][1]; w.z = o[n][2]; w.w = o[n][3];
            *reinterpret_cast<float4*>(&Ol[l15 * 68 + n * 16 + lg * 4]) = w;
        }
        const size_t rowbase = ((size_t)h * 32 + (qb - 32)) * 64;
        const size_t segR = (size_t)NH * 32 * 64;
        if (lane < 16)
            Mp[seg * segR + rowbase + wave * 16 + l15] = make_float2(mrun, lsum);
#pragma unroll
        for (int kk = 0; kk < 2; ++kk) {
            int r = (lane >> 3) + kk * 8;         // 0..15
            int c0 = (lane & 7) * 8;              // 8-col group
            float4 a = *reinterpret_cast<const float4*>(&Ol[r * 68 + c0]);
            float4 b = *reinterpret_cast<const float4*>(&Ol[r * 68 + c0 + 4]);
            short8 v;
            v[0] = f2bf(a.x); v[1] = f2bf(a.y); v[2] = f2bf(a.z); v[3] = f2bf(a.w);
            v[4] = f2bf(b.x); v[5] = f2bf(b.y); v[6] = f2bf(b.z); v[7] = f2bf(b.w);
            *reinterpret_cast<short8*>(
                &Op[(seg * segR + rowbase + wave * 16 + r) * 64 + c0]) = v;
        }
    } else {
        float inv = 1.f / lsum;
#pragma unroll
        for (int n = 0; n < 4; ++n) {
            float4 w;
            w.x = o[n][0] * inv; w.y = o[n][1] * inv;
            w.z = o[n][2] * inv; w.w = o[n][3] * inv;
            *reinterpret_cast<float4*>(&Ol[l15 * 68 + n * 16 + lg * 4]) = w;
        }
#pragma unroll
        for (int kk = 0; kk < 4; ++kk) {
            int r = lane >> 2, c0 = (lane & 3) * 4 + kk * 16;
            float4 v = *reinterpret_cast<const float4*>(&Ol[r * 68 + c0]);
            short4 b;
            b.x = f2bf(v.x); b.y = f2bf(v.y); b.z = f2bf(v.z); b.w = f2bf(v.w);
            *reinterpret_cast<short4*>(
                &Aout[(size_t)(q0w + r) * DM + h * DKH + c0]) = b;
        }
    }
}

// Merge the 2 kv-segments for qb >= 32 (bf16 partials). grid = 12*32 x 256.
__global__ __launch_bounds__(256) void combine_k(const short* __restrict__ Op,
                                                 const float2* __restrict__ Mp,
                                                 short* __restrict__ Aout) {
    const int h = blockIdx.x / 32, qbr = blockIdx.x % 32;
    const int t = threadIdx.x;
    const int row = t >> 2, c0 = (t & 3) * 16;
    const size_t rowbase = ((size_t)h * 32 + qbr) * 64 + row;
    const size_t segR = (size_t)NH * 32 * 64;
    float2 ml0 = Mp[rowbase], ml1 = Mp[segR + rowbase];
    float m = fmaxf(ml0.x, ml1.x);
    float s0 = exp2f(ml0.x - m), s1 = exp2f(ml1.x - m);
    float inv = 1.f / (s0 * ml0.y + s1 * ml1.y);
    const short* O0 = Op + rowbase * 64;
    const short* O1 = Op + (segR + rowbase) * 64;
    const int q = (32 + qbr) * 64 + row;
#pragma unroll
    for (int i = 0; i < 2; ++i) {
        int d = c0 + i * 8;
        short8 a = *reinterpret_cast<const short8*>(O0 + d);
        short8 b = *reinterpret_cast<const short8*>(O1 + d);
        short8 r;
#pragma unroll
        for (int e = 0; e < 8; ++e)
            r[e] = f2bf((bf2f(a[e]) * s0 + bf2f(b[e]) * s1) * inv);
        *reinterpret_cast<short8*>(&Aout[(size_t)q * DM + h * DKH + d]) = r;
    }
}

// ---------------------------------------------------------------- launcher
extern "C" void kernel_launch(void* const* d_in, const int* in_sizes, int n_in,
                              void* d_out, int out_size, void* d_ws, size_t ws_size,
                              hipStream_t stream) {
    const float* X  = (const float*)d_in[0];
    const int*   pos = (const int*)d_in[1];
    const float* Wq = (const float*)d_in[2];
    const float* Wk = (const float*)d_in[3];
    const float* Wv = (const float*)d_in[4];
    const float* Wo = (const float*)d_in[5];
    float* out = (float*)d_out;

    char* ws = (char*)d_ws;
    short* Xbf = (short*)ws;  ws += (size_t)S_LEN * DM * 2;
    short* Wqb = (short*)ws;  ws += (size_t)DM * DM * 2;
    short* Wkb = (short*)ws;  ws += (size_t)DM * DM * 2;
    short* Wvb = (short*)ws;  ws += (size_t)DM * DM * 2;
    short* Wob = (short*)ws;  ws += (size_t)DM * DM * 2;
    float2* rt = (float2*)ws; ws += (size_t)S_LEN * 32 * 8;
    short* Qb  = (short*)ws;  ws += (size_t)NH * S_LEN * DKH * 2;
    short* Kb  = (short*)ws;  ws += (size_t)NH * S_LEN * DKH * 2;
    short* Vtb = (short*)ws;  ws += (size_t)NH * S_LEN * DKH * 2;
    short* Ab  = (short*)ws;  ws += (size_t)S_LEN * DM * 2;
    short* Op  = (short*)ws;  ws += (size_t)2 * NH * 32 * 64 * 64 * 2;  // 6.3 MB
    float2* Mp = (float2*)ws; ws += (size_t)2 * NH * 32 * 64 * 8;       // 0.4 MB

    prep_k<<<5888, 256, 0, stream>>>(X, Wq, Wk, Wv, Wo, pos,
                                     Xbf, Wqb, Wkb, Wvb, Wob, rt);
    gemm_qkv_k<<<dim3(6, 32, 3), 256, 0, stream>>>(Xbf, Wqb, Wkb, Wvb, rt, Qb, Kb, Vtb);
    attn_k<<<dim3(96 * NH), 256, 0, stream>>>(Qb, Kb, Vtb, Ab, Op, Mp);
    combine_k<<<dim3(NH * 32), 256, 0, stream>>>(Op, Mp, Ab);
    gemm_out_k<<<dim3(6, 32), 256, 0, stream>>>(Ab, Wob, out);
}